// Round 4
// baseline (4733.488 us; speedup 1.0000x reference)
//
#include <hip/hip_runtime.h>
#include <stdint.h>

// ---------------------------------------------------------------------------
// BesselConv2d on MI355X (gfx950)
//
// k1: pad+convert x (fp32 NCHW) -> xp bf16 NHWC, zero-padded to 72x72.
// k2: build Wfb[tap][ch'][cin] bf16, ch' = cout*32 + (part*16+m).
// k3: implicit-GEMM conv, 128x128 block tile, 4 waves, 16x16x32 bf16 MFMA
//     (R2's verified fragment/epilogue structure), fused square/group-
//     reduce/bias epilogue.
//
// R4 changes vs R2 (R3's bundled 32x32 rewrite regressed: spills + WRITE
// amplification; reverted):
//  - B fragments now load DIRECTLY global->VGPR from the L2-resident Wfb
//    slice (16x64B aligned txns/instr, L1 catches kk=1 + sibling wave).
//    Removes B LDS staging + B ds_reads + the per-tap barrier: only the
//    per-dy A staging barriers remain (18 vs 162 per block).
//  - A-row sliding kept: stage 2 full 72-px rows per dy, slide by dx in
//    LDS. A swizzle read key becomes (lr+dx)&7 (still conflict-free).
// ---------------------------------------------------------------------------

typedef unsigned short ushort_t;
typedef __attribute__((ext_vector_type(8))) short short8;   // 8 bf16 = 4 VGPRs
typedef __attribute__((ext_vector_type(4))) float float4v;  // 4 fp32 acc

typedef const void __attribute__((address_space(1)))* gptr_t;
typedef void __attribute__((address_space(3)))* sptr_t;

__device__ __forceinline__ ushort_t f2bf(float f) {
    union { float f; uint32_t u; } v; v.f = f;
    uint32_t u = v.u;
    u += 0x7fffu + ((u >> 16) & 1u);   // round-to-nearest-even
    return (ushort_t)(u >> 16);
}

// ---------------------------------------------------------------------------
// Kernel 1: x[32][64][64][64] (NCHW fp32) -> xp[32][72][72][64] (NHWC bf16)
// ---------------------------------------------------------------------------
__global__ __launch_bounds__(256) void pad_kernel(const float* __restrict__ x,
                                                  ushort_t* __restrict__ xp) {
    __shared__ float lds[64 * 65];
    const int hp  = blockIdx.x;   // 0..71
    const int b   = blockIdx.y;   // 0..31
    const int tid = threadIdx.x;
    const int h   = hp - 4;
    const bool hvalid = (h >= 0 && h < 64);
    if (hvalid) {
        #pragma unroll
        for (int it = 0; it < 16; ++it) {
            int idx = it * 256 + tid;
            int cin = idx >> 6, w = idx & 63;
            lds[w * 65 + cin] = x[((b * 64 + cin) * 64 + h) * 64 + w];
        }
    }
    __syncthreads();
    #pragma unroll
    for (int it = 0; it < 18; ++it) {
        int o = it * 256 + tid;
        int wp = o >> 6, cin = o & 63;
        int w = wp - 4;
        float val = (hvalid && w >= 0 && w < 64) ? lds[w * 65 + cin] : 0.0f;
        xp[((b * 72 + hp) * 72 + wp) * 64 + cin] = f2bf(val);
    }
}

// ---------------------------------------------------------------------------
// Kernel 2: Wfb[t][ch'][cin] bf16, ch' = cout*32 + g, g = part*16 + m.
// ---------------------------------------------------------------------------
__global__ __launch_bounds__(256) void wf_kernel(const float* __restrict__ Tr,
                                                 const float* __restrict__ Ti,
                                                 const float* __restrict__ wr,
                                                 const float* __restrict__ wi,
                                                 ushort_t* __restrict__ Wfb) {
    __shared__ float lds[64 * 65];
    const int g   = blockIdx.x;        // 0..31
    const int t   = blockIdx.y;        // 0..80
    const int part = g >> 4, m = g & 15;
    const int tid = threadIdx.x;
    #pragma unroll
    for (int it = 0; it < 16; ++it) {
        int cc = it * 256 + tid;       // cin*64 + cout
        float acc = 0.f;
        #pragma unroll
        for (int j = 0; j < 8; ++j) {
            float tr  = Tr[(m * 81 + t) * 8 + j];
            float ti  = Ti[(m * 81 + t) * 8 + j];
            float wrv = wr[(m * 8 + j) * 4096 + cc];
            float wiv = wi[(m * 8 + j) * 4096 + cc];
            acc += (part == 0) ? (tr * wrv - ti * wiv) : (tr * wiv + ti * wrv);
        }
        lds[(cc & 63) * 65 + (cc >> 6)] = acc;
    }
    __syncthreads();
    #pragma unroll
    for (int it = 0; it < 16; ++it) {
        int o = it * 256 + tid;        // cout*64 + cin
        int cout = o >> 6, cin = o & 63;
        Wfb[(t * 2048 + cout * 32 + g) * 64 + cin] = f2bf(lds[cout * 65 + cin]);
    }
}

// ---------------------------------------------------------------------------
// Kernel 3: implicit-GEMM conv.
// As: 2 full padded rows [2][72][64] bf16, XOR-16B-seg swizzled (key = px&7).
// B: direct global loads from Wfb (L2-resident per-ct slice).
// ---------------------------------------------------------------------------
__global__ __launch_bounds__(256, 3) void conv_kernel(const ushort_t* __restrict__ xp,
                                                      const ushort_t* __restrict__ Wfb,
                                                      const float* __restrict__ bias,
                                                      float* __restrict__ out) {
    __shared__ alignas(16) ushort_t As[2 * 72 * 64];   // 18 KB

    const int pt   = blockIdx.x;        // 0..1023 (fast -> same-ct blocks concurrent)
    const int ct   = blockIdx.y;        // 0..15
    const int b    = pt >> 5;
    const int h0   = (pt & 31) * 2;     // output rows h0, h0+1
    const int tid  = threadIdx.x;
    const int wv   = tid >> 6;
    const int lane = tid & 63;
    const int wrow = wv >> 1, wcol = wv & 1;   // output row half / channel half
    const int quad = lane >> 4, lr = lane & 15;
    // write-side swizzle for global_load_lds source lanes
    const int lsw  = ((lane & ~7) | ((lane ^ (lane >> 3)) & 7)) * 16;

    float4v acc[4][4];
    #pragma unroll
    for (int i = 0; i < 4; ++i)
        #pragma unroll
        for (int j = 0; j < 4; ++j) {
            float4v z = {0.f, 0.f, 0.f, 0.f};
            acc[i][j] = z;
        }

    const char* xpb = (const char*)xp;
    // B base for this block's channel tile; + t*262144 + row*128 + seg*16
    const char* wfbase = (const char*)Wfb + (size_t)(ct * 128) * 128
                                          + (size_t)(wcol * 64 + lr) * 128
                                          + (size_t)quad * 16;

    for (int dy = 0; dy < 9; ++dy) {
        __syncthreads();   // previous dy's As readers done
        // stage A: input rows h0+dy, h0+dy+1 (72 px * 128 B = 9 chunks each)
        #pragma unroll
        for (int k2 = 0; k2 < 5; ++k2) {
            const int c = wv + 4 * k2;          // 18 chunks over 4 waves
            if (c < 18) {
                const int r  = (c >= 9) ? 1 : 0;
                const int cs = c - 9 * r;
                const char* g = xpb
                    + (size_t)((b * 72 + h0 + dy + r) * 72) * 128
                    + (size_t)cs * 1024 + (size_t)lsw;
                __builtin_amdgcn_global_load_lds((gptr_t)g,
                    (sptr_t)((char*)As + c * 1024), 16, 0, 0);
            }
        }
        __syncthreads();   // As ready (drains the global_load_lds)

        for (int dx = 0; dx < 9; ++dx) {
            const char* wt = wfbase + (size_t)(dy * 9 + dx) * 262144;
            const int key  = (lr + dx) & 7;     // A swizzle read key
            const int pbase = wrow * 72 + lr + dx;
            #pragma unroll
            for (int kk = 0; kk < 2; ++kk) {
                short8 a[4], bb[4];
                const int slot = ((kk * 4 + quad) ^ key) * 8;
                #pragma unroll
                for (int j = 0; j < 4; ++j)
                    bb[j] = *(const short8*)(wt + (size_t)(j * 16) * 128
                                                + (size_t)kk * 64);
                #pragma unroll
                for (int i = 0; i < 4; ++i)
                    a[i] = *(const short8*)&As[(pbase + i * 16) * 64 + slot];
                #pragma unroll
                for (int i = 0; i < 4; ++i)
                    #pragma unroll
                    for (int j = 0; j < 4; ++j)
                        acc[i][j] = __builtin_amdgcn_mfma_f32_16x16x32_bf16(
                            a[i], bb[j], acc[i][j], 0, 0, 0);
            }
        }
    }

    // Epilogue (R2's verified form): wave's 64 channels = 2 couts x 32 groups.
    const int c0 = ct * 4 + wcol * 2;
    const float b0 = bias[c0], b1 = bias[c0 + 1];
    #pragma unroll
    for (int i = 0; i < 4; ++i) {
        #pragma unroll
        for (int reg = 0; reg < 4; ++reg) {
            float v0 = acc[i][0][reg] * acc[i][0][reg] + acc[i][1][reg] * acc[i][1][reg];
            float v1 = acc[i][2][reg] * acc[i][2][reg] + acc[i][3][reg] * acc[i][3][reg];
            #pragma unroll
            for (int off = 1; off <= 8; off <<= 1) {
                v0 += __shfl_xor(v0, off, 64);
                v1 += __shfl_xor(v1, off, 64);
            }
            if (lr == 0) {
                const int w = i * 16 + quad * 4 + reg;
                const int h = h0 + wrow;
                out[((b * 64 + c0    ) * 64 + h) * 64 + w] = v0 + b0;
                out[((b * 64 + c0 + 1) * 64 + h) * 64 + w] = v1 + b1;
            }
        }
    }
}

// ---------------------------------------------------------------------------
extern "C" void kernel_launch(void* const* d_in, const int* in_sizes, int n_in,
                              void* d_out, int out_size, void* d_ws, size_t ws_size,
                              hipStream_t stream) {
    const float* x    = (const float*)d_in[0];
    const float* Tr   = (const float*)d_in[1];
    const float* Ti   = (const float*)d_in[2];
    const float* wr   = (const float*)d_in[3];
    const float* wi   = (const float*)d_in[4];
    const float* bias = (const float*)d_in[5];
    float* out = (float*)d_out;

    ushort_t* xp  = (ushort_t*)d_ws;                          // 21,233,664 B
    ushort_t* Wfb = (ushort_t*)((char*)d_ws + 21233664);      // 21,233,664 B

    pad_kernel<<<dim3(72, 32), 256, 0, stream>>>(x, xp);
    wf_kernel<<<dim3(32, 81), 256, 0, stream>>>(Tr, Ti, wr, wi, Wfb);
    conv_kernel<<<dim3(1024, 16), 256, 0, stream>>>(xp, Wfb, bias, out);
}

// Round 5
// 2172.166 us; speedup vs baseline: 2.1792x; 2.1792x over previous
//
#include <hip/hip_runtime.h>
#include <stdint.h>

// ---------------------------------------------------------------------------
// BesselConv2d on MI355X (gfx950)
//
// k1: pad+convert x (fp32 NCHW) -> xp bf16 NHWC, zero-padded to 72x72.
// k2: build Wfb[tap][ch'][cin] bf16, ch' = cout*32 + (part*16+m).
// k3: implicit-GEMM conv, 128x128 block tile, 4 waves, 16x16x32 bf16 MFMA,
//     fused square/group-reduce/bias epilogue. R2's verified compute core.
//
// R5 changes vs R2 (R3 = spills, R4 = latency-bound direct B loads; both
// reverted):
//  - A-row sliding: stage 2 full 72-px rows once per dy (18 KB, single
//    buffer), slide the 64-px window by dx in LDS. Read key (lr+dx)&7.
//    A staging traffic drops 8x.
//  - B double-buffered (2 x 16 KB) with one-tap-ahead prefetch: loads for
//    tap t+1 issue BEFORE compute(t), so the vmcnt drain at the next
//    barrier overlaps a full tap of MFMA. Barriers: 162 -> 89 per block
//    (only 9 dy-boundary stalls are synchronous).
// ---------------------------------------------------------------------------

typedef unsigned short ushort_t;
typedef __attribute__((ext_vector_type(8))) short short8;   // 8 bf16 = 4 VGPRs
typedef __attribute__((ext_vector_type(4))) float float4v;  // 4 fp32 acc

typedef const void __attribute__((address_space(1)))* gptr_t;
typedef void __attribute__((address_space(3)))* sptr_t;

__device__ __forceinline__ ushort_t f2bf(float f) {
    union { float f; uint32_t u; } v; v.f = f;
    uint32_t u = v.u;
    u += 0x7fffu + ((u >> 16) & 1u);   // round-to-nearest-even
    return (ushort_t)(u >> 16);
}

// ---------------------------------------------------------------------------
// Kernel 1: x[32][64][64][64] (NCHW fp32) -> xp[32][72][72][64] (NHWC bf16)
// ---------------------------------------------------------------------------
__global__ __launch_bounds__(256) void pad_kernel(const float* __restrict__ x,
                                                  ushort_t* __restrict__ xp) {
    __shared__ float lds[64 * 65];
    const int hp  = blockIdx.x;   // 0..71
    const int b   = blockIdx.y;   // 0..31
    const int tid = threadIdx.x;
    const int h   = hp - 4;
    const bool hvalid = (h >= 0 && h < 64);
    if (hvalid) {
        #pragma unroll
        for (int it = 0; it < 16; ++it) {
            int idx = it * 256 + tid;
            int cin = idx >> 6, w = idx & 63;
            lds[w * 65 + cin] = x[((b * 64 + cin) * 64 + h) * 64 + w];
        }
    }
    __syncthreads();
    #pragma unroll
    for (int it = 0; it < 18; ++it) {
        int o = it * 256 + tid;
        int wp = o >> 6, cin = o & 63;
        int w = wp - 4;
        float val = (hvalid && w >= 0 && w < 64) ? lds[w * 65 + cin] : 0.0f;
        xp[((b * 72 + hp) * 72 + wp) * 64 + cin] = f2bf(val);
    }
}

// ---------------------------------------------------------------------------
// Kernel 2: Wfb[t][ch'][cin] bf16, ch' = cout*32 + g, g = part*16 + m.
// ---------------------------------------------------------------------------
__global__ __launch_bounds__(256) void wf_kernel(const float* __restrict__ Tr,
                                                 const float* __restrict__ Ti,
                                                 const float* __restrict__ wr,
                                                 const float* __restrict__ wi,
                                                 ushort_t* __restrict__ Wfb) {
    __shared__ float lds[64 * 65];
    const int g   = blockIdx.x;        // 0..31
    const int t   = blockIdx.y;        // 0..80
    const int part = g >> 4, m = g & 15;
    const int tid = threadIdx.x;
    #pragma unroll
    for (int it = 0; it < 16; ++it) {
        int cc = it * 256 + tid;       // cin*64 + cout
        float acc = 0.f;
        #pragma unroll
        for (int j = 0; j < 8; ++j) {
            float tr  = Tr[(m * 81 + t) * 8 + j];
            float ti  = Ti[(m * 81 + t) * 8 + j];
            float wrv = wr[(m * 8 + j) * 4096 + cc];
            float wiv = wi[(m * 8 + j) * 4096 + cc];
            acc += (part == 0) ? (tr * wrv - ti * wiv) : (tr * wiv + ti * wrv);
        }
        lds[(cc & 63) * 65 + (cc >> 6)] = acc;
    }
    __syncthreads();
    #pragma unroll
    for (int it = 0; it < 16; ++it) {
        int o = it * 256 + tid;        // cout*64 + cin
        int cout = o >> 6, cin = o & 63;
        Wfb[(t * 2048 + cout * 32 + g) * 64 + cin] = f2bf(lds[cout * 65 + cin]);
    }
}

// ---------------------------------------------------------------------------
// Kernel 3: implicit-GEMM conv.
// As: 2 full padded rows [2][72][64] (XOR-16B-seg swizzled, key = px&7).
// Bs: double-buffered per-tap tile [2][128][64] (key = ch&7), prefetched
// one tap ahead.
// ---------------------------------------------------------------------------
__global__ __launch_bounds__(256, 3) void conv_kernel(const ushort_t* __restrict__ xp,
                                                      const ushort_t* __restrict__ Wfb,
                                                      const float* __restrict__ bias,
                                                      float* __restrict__ out) {
    __shared__ alignas(16) ushort_t As[2 * 72 * 64];       // 18 KB
    __shared__ alignas(16) ushort_t Bs[2 * 128 * 64];      // 32 KB (dbuf)

    const int pt   = blockIdx.x;        // 0..1023 (fast -> same-ct blocks concurrent)
    const int ct   = blockIdx.y;        // 0..15
    const int b    = pt >> 5;
    const int h0   = (pt & 31) * 2;     // output rows h0, h0+1
    const int tid  = threadIdx.x;
    const int wv   = tid >> 6;
    const int lane = tid & 63;
    const int wrow = wv >> 1, wcol = wv & 1;
    const int quad = lane >> 4, lr = lane & 15;
    const int lsw  = ((lane & ~7) | ((lane ^ (lane >> 3)) & 7)) * 16;

    float4v acc[4][4];
    #pragma unroll
    for (int i = 0; i < 4; ++i)
        #pragma unroll
        for (int j = 0; j < 4; ++j) {
            float4v z = {0.f, 0.f, 0.f, 0.f};
            acc[i][j] = z;
        }

    const char* xpb  = (const char*)xp;
    const char* wfb0 = (const char*)Wfb + (size_t)(ct * 128) * 128;  // +t*262144

    // --- staging helpers (inlined lambdas) ---
    auto stageA = [&](int dy) {
        #pragma unroll
        for (int k2 = 0; k2 < 5; ++k2) {
            const int c = wv + 4 * k2;          // 18 chunks over 4 waves
            if (c < 18) {
                const int r  = (c >= 9) ? 1 : 0;
                const int cs = c - 9 * r;
                const char* g = xpb
                    + (size_t)((b * 72 + h0 + dy + r) * 72) * 128
                    + (size_t)cs * 1024 + (size_t)lsw;
                __builtin_amdgcn_global_load_lds((gptr_t)g,
                    (sptr_t)((char*)As + c * 1024), 16, 0, 0);
            }
        }
    };
    auto stageB = [&](int t) {
        const char* base = wfb0 + (size_t)t * 262144;
        char* dst = (char*)Bs + (t & 1) * 16384;
        #pragma unroll
        for (int k2 = 0; k2 < 4; ++k2) {
            const int c2 = wv * 4 + k2;
            __builtin_amdgcn_global_load_lds((gptr_t)(base + (size_t)c2 * 1024 + (size_t)lsw),
                (sptr_t)(dst + c2 * 1024), 16, 0, 0);
        }
    };

    // prologue: stage A(dy=0) + B(t=0)
    stageA(0);
    stageB(0);

    for (int dy = 0; dy < 9; ++dy) {
        for (int dx = 0; dx < 9; ++dx) {
            const int t = dy * 9 + dx;
            __syncthreads();              // staging(t) drained; compute(t-1) done
            if (t < 80 && dx < 8) stageB(t + 1);   // prefetch next tap

            // compute tap t
            const ushort_t* Bp = Bs + (t & 1) * 8192;
            const int akey  = (lr + dx) & 7;
            const int bkey  = lr & 7;
            const int pbase = wrow * 72 + lr + dx;
            #pragma unroll
            for (int kk = 0; kk < 2; ++kk) {
                short8 a[4], bb[4];
                const int aslot = ((kk * 4 + quad) ^ akey) * 8;
                const int bslot = ((kk * 4 + quad) ^ bkey) * 8;
                #pragma unroll
                for (int j = 0; j < 4; ++j)
                    bb[j] = *(const short8*)&Bp[(wcol * 64 + j * 16 + lr) * 64 + bslot];
                #pragma unroll
                for (int i = 0; i < 4; ++i)
                    a[i] = *(const short8*)&As[(pbase + i * 16) * 64 + aslot];
                #pragma unroll
                for (int i = 0; i < 4; ++i)
                    #pragma unroll
                    for (int j = 0; j < 4; ++j)
                        acc[i][j] = __builtin_amdgcn_mfma_f32_16x16x32_bf16(
                            a[i], bb[j], acc[i][j], 0, 0, 0);
            }

            if (t < 80 && dx == 8) {
                __syncthreads();          // all waves done reading As(dy)
                stageA(dy + 1);
                stageB(t + 1);
            }
        }
    }

    // Epilogue (R2's verified form): wave's 64 channels = 2 couts x 32 groups.
    const int c0 = ct * 4 + wcol * 2;
    const float b0 = bias[c0], b1 = bias[c0 + 1];
    #pragma unroll
    for (int i = 0; i < 4; ++i) {
        #pragma unroll
        for (int reg = 0; reg < 4; ++reg) {
            float v0 = acc[i][0][reg] * acc[i][0][reg] + acc[i][1][reg] * acc[i][1][reg];
            float v1 = acc[i][2][reg] * acc[i][2][reg] + acc[i][3][reg] * acc[i][3][reg];
            #pragma unroll
            for (int off = 1; off <= 8; off <<= 1) {
                v0 += __shfl_xor(v0, off, 64);
                v1 += __shfl_xor(v1, off, 64);
            }
            if (lr == 0) {
                const int w = i * 16 + quad * 4 + reg;
                const int h = h0 + wrow;
                out[((b * 64 + c0    ) * 64 + h) * 64 + w] = v0 + b0;
                out[((b * 64 + c0 + 1) * 64 + h) * 64 + w] = v1 + b1;
            }
        }
    }
}

// ---------------------------------------------------------------------------
extern "C" void kernel_launch(void* const* d_in, const int* in_sizes, int n_in,
                              void* d_out, int out_size, void* d_ws, size_t ws_size,
                              hipStream_t stream) {
    const float* x    = (const float*)d_in[0];
    const float* Tr   = (const float*)d_in[1];
    const float* Ti   = (const float*)d_in[2];
    const float* wr   = (const float*)d_in[3];
    const float* wi   = (const float*)d_in[4];
    const float* bias = (const float*)d_in[5];
    float* out = (float*)d_out;

    ushort_t* xp  = (ushort_t*)d_ws;                          // 21,233,664 B
    ushort_t* Wfb = (ushort_t*)((char*)d_ws + 21233664);      // 21,233,664 B

    pad_kernel<<<dim3(72, 32), 256, 0, stream>>>(x, xp);
    wf_kernel<<<dim3(32, 81), 256, 0, stream>>>(Tr, Ti, wr, wi, Wfb);
    conv_kernel<<<dim3(1024, 16), 256, 0, stream>>>(xp, Wfb, bias, out);
}

// Round 6
// 2107.191 us; speedup vs baseline: 2.2463x; 1.0308x over previous
//
#include <hip/hip_runtime.h>
#include <stdint.h>

// ---------------------------------------------------------------------------
// BesselConv2d on MI355X (gfx950)
//
// k1: pad+convert x (fp32 NCHW) -> xp bf16 NHWC, zero-padded to 72x72.
// k2: build Wfb[tap][ch'][cin] bf16, ch' = cout*32 + (part*16+m).
// k3: implicit-GEMM conv, fused square/group-reduce/bias epilogue.
//
// R6 change vs R5: wave tile 64x64 -> 128x64 (block 256px x 128ch, 4 output
// rows). LDS fragment-read B/FLOP drops 25% (R5 rocprof: LDS pipe ~88% busy
// = the bottleneck; MfmaUtil 67%). Cost: ~2 waves/SIMD occupancy — relies
// on cross-wave MFMA/LDS pipe overlap (m114). A-sliding, XOR swizzle, B
// double-buffer prefetch pipeline all carried over from R5.
// ---------------------------------------------------------------------------

typedef unsigned short ushort_t;
typedef __attribute__((ext_vector_type(8))) short short8;   // 8 bf16 = 4 VGPRs
typedef __attribute__((ext_vector_type(4))) float float4v;  // 4 fp32 acc

typedef const void __attribute__((address_space(1)))* gptr_t;
typedef void __attribute__((address_space(3)))* sptr_t;

__device__ __forceinline__ ushort_t f2bf(float f) {
    union { float f; uint32_t u; } v; v.f = f;
    uint32_t u = v.u;
    u += 0x7fffu + ((u >> 16) & 1u);   // round-to-nearest-even
    return (ushort_t)(u >> 16);
}

// ---------------------------------------------------------------------------
// Kernel 1: x[32][64][64][64] (NCHW fp32) -> xp[32][72][72][64] (NHWC bf16)
// ---------------------------------------------------------------------------
__global__ __launch_bounds__(256) void pad_kernel(const float* __restrict__ x,
                                                  ushort_t* __restrict__ xp) {
    __shared__ float lds[64 * 65];
    const int hp  = blockIdx.x;   // 0..71
    const int b   = blockIdx.y;   // 0..31
    const int tid = threadIdx.x;
    const int h   = hp - 4;
    const bool hvalid = (h >= 0 && h < 64);
    if (hvalid) {
        #pragma unroll
        for (int it = 0; it < 16; ++it) {
            int idx = it * 256 + tid;
            int cin = idx >> 6, w = idx & 63;
            lds[w * 65 + cin] = x[((b * 64 + cin) * 64 + h) * 64 + w];
        }
    }
    __syncthreads();
    #pragma unroll
    for (int it = 0; it < 18; ++it) {
        int o = it * 256 + tid;
        int wp = o >> 6, cin = o & 63;
        int w = wp - 4;
        float val = (hvalid && w >= 0 && w < 64) ? lds[w * 65 + cin] : 0.0f;
        xp[((b * 72 + hp) * 72 + wp) * 64 + cin] = f2bf(val);
    }
}

// ---------------------------------------------------------------------------
// Kernel 2: Wfb[t][ch'][cin] bf16, ch' = cout*32 + g, g = part*16 + m.
// ---------------------------------------------------------------------------
__global__ __launch_bounds__(256) void wf_kernel(const float* __restrict__ Tr,
                                                 const float* __restrict__ Ti,
                                                 const float* __restrict__ wr,
                                                 const float* __restrict__ wi,
                                                 ushort_t* __restrict__ Wfb) {
    __shared__ float lds[64 * 65];
    const int g   = blockIdx.x;        // 0..31
    const int t   = blockIdx.y;        // 0..80
    const int part = g >> 4, m = g & 15;
    const int tid = threadIdx.x;
    #pragma unroll
    for (int it = 0; it < 16; ++it) {
        int cc = it * 256 + tid;       // cin*64 + cout
        float acc = 0.f;
        #pragma unroll
        for (int j = 0; j < 8; ++j) {
            float tr  = Tr[(m * 81 + t) * 8 + j];
            float ti  = Ti[(m * 81 + t) * 8 + j];
            float wrv = wr[(m * 8 + j) * 4096 + cc];
            float wiv = wi[(m * 8 + j) * 4096 + cc];
            acc += (part == 0) ? (tr * wrv - ti * wiv) : (tr * wiv + ti * wrv);
        }
        lds[(cc & 63) * 65 + (cc >> 6)] = acc;
    }
    __syncthreads();
    #pragma unroll
    for (int it = 0; it < 16; ++it) {
        int o = it * 256 + tid;        // cout*64 + cin
        int cout = o >> 6, cin = o & 63;
        Wfb[(t * 2048 + cout * 32 + g) * 64 + cin] = f2bf(lds[cout * 65 + cin]);
    }
}

// ---------------------------------------------------------------------------
// Kernel 3: implicit-GEMM conv.
// Block: 256 px (4 output rows) x 128 ch. Wave: 128 px x 64 ch.
// As: 4 padded rows [4][72][64] (XOR-16B-seg swizzled, key = px&7), per dy.
// Bs: double-buffered per-tap tile [2][128][64] (key = ch&7), prefetched.
// ---------------------------------------------------------------------------
__global__ __launch_bounds__(256, 2) void conv_kernel(const ushort_t* __restrict__ xp,
                                                      const ushort_t* __restrict__ Wfb,
                                                      const float* __restrict__ bias,
                                                      float* __restrict__ out) {
    __shared__ alignas(16) ushort_t As[4 * 72 * 64];       // 36 KB
    __shared__ alignas(16) ushort_t Bs[2 * 128 * 64];      // 32 KB (dbuf)

    const int pt   = blockIdx.x;        // 0..511 (fast -> same-ct blocks concurrent)
    const int ct   = blockIdx.y;        // 0..15
    const int b    = pt >> 4;
    const int h0   = (pt & 15) * 4;     // output rows h0..h0+3
    const int tid  = threadIdx.x;
    const int wv   = tid >> 6;
    const int lane = tid & 63;
    const int wrow = wv >> 1, wcol = wv & 1;   // px half (2 rows) / ch half
    const int quad = lane >> 4, lr = lane & 15;
    const int lsw  = ((lane & ~7) | ((lane ^ (lane >> 3)) & 7)) * 16;

    float4v acc[8][4];
    #pragma unroll
    for (int i = 0; i < 8; ++i)
        #pragma unroll
        for (int j = 0; j < 4; ++j) {
            float4v z = {0.f, 0.f, 0.f, 0.f};
            acc[i][j] = z;
        }

    const char* xpb  = (const char*)xp;
    const char* wfb0 = (const char*)Wfb + (size_t)(ct * 128) * 128;  // +t*262144

    auto stageA = [&](int dy) {
        // 4 rows x 9 KB = 36 chunks of 1 KB over 4 waves
        #pragma unroll
        for (int k2 = 0; k2 < 9; ++k2) {
            const int c  = wv + 4 * k2;
            const int r  = c / 9;
            const int cs = c - 9 * r;
            const char* g = xpb
                + (size_t)((b * 72 + h0 + dy + r) * 72) * 128
                + (size_t)cs * 1024 + (size_t)lsw;
            __builtin_amdgcn_global_load_lds((gptr_t)g,
                (sptr_t)((char*)As + c * 1024), 16, 0, 0);
        }
    };
    auto stageB = [&](int t) {
        const char* base = wfb0 + (size_t)t * 262144;
        char* dst = (char*)Bs + (t & 1) * 16384;
        #pragma unroll
        for (int k2 = 0; k2 < 4; ++k2) {
            const int c2 = wv * 4 + k2;
            __builtin_amdgcn_global_load_lds((gptr_t)(base + (size_t)c2 * 1024 + (size_t)lsw),
                (sptr_t)(dst + c2 * 1024), 16, 0, 0);
        }
    };

    stageA(0);
    stageB(0);

    for (int dy = 0; dy < 9; ++dy) {
        for (int dx = 0; dx < 9; ++dx) {
            const int t = dy * 9 + dx;
            __syncthreads();              // staging(t) drained; compute(t-1) done
            if (t < 80 && dx < 8) stageB(t + 1);   // prefetch next tap

            const ushort_t* Bp = Bs + (t & 1) * 8192;
            const int akey = (lr + dx) & 7;
            const int bkey = lr & 7;
            // A rows for acc block i: As slot = wrow*2 + (i>>2), px = (i&3)*16+lr+dx
            const int abase = wrow * 2 * 72 + lr + dx;
            #pragma unroll
            for (int kk = 0; kk < 2; ++kk) {
                short8 a[8], bb[4];
                const int aslot = ((kk * 4 + quad) ^ akey) * 8;
                const int bslot = ((kk * 4 + quad) ^ bkey) * 8;
                #pragma unroll
                for (int j = 0; j < 4; ++j)
                    bb[j] = *(const short8*)&Bp[(wcol * 64 + j * 16 + lr) * 64 + bslot];
                #pragma unroll
                for (int i = 0; i < 8; ++i)
                    a[i] = *(const short8*)&As[(abase + (i >> 2) * 72 + (i & 3) * 16) * 64 + aslot];
                #pragma unroll
                for (int i = 0; i < 8; ++i)
                    #pragma unroll
                    for (int j = 0; j < 4; ++j)
                        acc[i][j] = __builtin_amdgcn_mfma_f32_16x16x32_bf16(
                            a[i], bb[j], acc[i][j], 0, 0, 0);
            }

            if (t < 80 && dx == 8) {
                __syncthreads();          // all waves done reading As(dy)
                stageA(dy + 1);
                stageB(t + 1);
            }
        }
    }

    // Epilogue: wave's 64 ch = 2 couts x 32 groups; 128 px = 2 output rows.
    const int c0 = ct * 4 + wcol * 2;
    const float b0 = bias[c0], b1 = bias[c0 + 1];
    #pragma unroll
    for (int i = 0; i < 8; ++i) {
        #pragma unroll
        for (int reg = 0; reg < 4; ++reg) {
            float v0 = acc[i][0][reg] * acc[i][0][reg] + acc[i][1][reg] * acc[i][1][reg];
            float v1 = acc[i][2][reg] * acc[i][2][reg] + acc[i][3][reg] * acc[i][3][reg];
            #pragma unroll
            for (int off = 1; off <= 8; off <<= 1) {
                v0 += __shfl_xor(v0, off, 64);
                v1 += __shfl_xor(v1, off, 64);
            }
            if (lr == 0) {
                const int w = (i & 3) * 16 + quad * 4 + reg;
                const int h = h0 + wrow * 2 + (i >> 2);
                out[((b * 64 + c0    ) * 64 + h) * 64 + w] = v0 + b0;
                out[((b * 64 + c0 + 1) * 64 + h) * 64 + w] = v1 + b1;
            }
        }
    }
}

// ---------------------------------------------------------------------------
extern "C" void kernel_launch(void* const* d_in, const int* in_sizes, int n_in,
                              void* d_out, int out_size, void* d_ws, size_t ws_size,
                              hipStream_t stream) {
    const float* x    = (const float*)d_in[0];
    const float* Tr   = (const float*)d_in[1];
    const float* Ti   = (const float*)d_in[2];
    const float* wr   = (const float*)d_in[3];
    const float* wi   = (const float*)d_in[4];
    const float* bias = (const float*)d_in[5];
    float* out = (float*)d_out;

    ushort_t* xp  = (ushort_t*)d_ws;                          // 21,233,664 B
    ushort_t* Wfb = (ushort_t*)((char*)d_ws + 21233664);      // 21,233,664 B

    pad_kernel<<<dim3(72, 32), 256, 0, stream>>>(x, xp);
    wf_kernel<<<dim3(32, 81), 256, 0, stream>>>(Tr, Ti, wr, wi, Wfb);
    conv_kernel<<<dim3(512, 16), 256, 0, stream>>>(xp, Wfb, bias, out);
}